// Round 2
// baseline (1434.947 us; speedup 1.0000x reference)
//
#include <hip/hip_runtime.h>
#include <hip/hip_bf16.h>

#define CDIM 256
#define NH 8
#define HDIM 32
#define HSTRIDE 1032  // LDS row stride (bf16 elems) for 16x1024 hidden tile; 2064B: 16B-aligned rows, 2-way-max bank aliasing

typedef short bf8 __attribute__((ext_vector_type(8)));
typedef float f32x4 __attribute__((ext_vector_type(4)));

__device__ __forceinline__ float bf2f(ushort u) {
  union { unsigned int i; float f; } x; x.i = ((unsigned int)u) << 16; return x.f;
}
__device__ __forceinline__ ushort f2bf(float f) {
  union { float f; unsigned int i; } x; x.f = f;
  unsigned int lsb = (x.i >> 16) & 1u;
  unsigned int r = x.i + 0x7fffu + lsb;
  return (ushort)(r >> 16);
}

// ---------------- weight cast fp32 -> bf16 ----------------
__global__ void k_cast(const float* __restrict__ s, ushort* __restrict__ d, int n) {
  int i = blockIdx.x * blockDim.x + threadIdx.x;
  if (i < n) d[i] = f2bf(s[i]);
}

// ---------------- CSR build ----------------
__global__ void k_hist(const int* __restrict__ dst, int E, int* __restrict__ deg) {
  int i = blockIdx.x * blockDim.x + threadIdx.x;
  if (i < E) atomicAdd(&deg[dst[i]], 1);
}

__global__ __launch_bounds__(1024) void k_scan1(const int* __restrict__ deg, int N,
                                                int* __restrict__ rowptr, int* __restrict__ bsum) {
  __shared__ int s[1024];
  int t = threadIdx.x;
  int i = blockIdx.x * 1024 + t;
  int val = (i < N) ? deg[i] : 0;
  s[t] = val;
  __syncthreads();
  for (int off = 1; off < 1024; off <<= 1) {
    int add = (t >= off) ? s[t - off] : 0;
    __syncthreads();
    s[t] += add;
    __syncthreads();
  }
  if (i < N) rowptr[i + 1] = s[t];
  if (t == 1023) bsum[blockIdx.x] = s[t];
}

__global__ void k_scan2(int* __restrict__ bsum, int nb) {
  if (threadIdx.x == 0 && blockIdx.x == 0) {
    int run = 0;
    for (int j = 0; j < nb; ++j) { int t = bsum[j]; bsum[j] = run; run += t; }
  }
}

__global__ void k_scan3(int* __restrict__ rowptr, const int* __restrict__ bsum, int N) {
  int i = blockIdx.x * blockDim.x + threadIdx.x;
  if (i < N) rowptr[i + 1] += bsum[i >> 10];
  if (i == 0) rowptr[0] = 0;
}

__global__ void k_scatter(const int* __restrict__ src, const int* __restrict__ dst, int E,
                          const int* __restrict__ rowptr, int* __restrict__ cur,
                          int* __restrict__ csr_src) {
  int i = blockIdx.x * blockDim.x + threadIdx.x;
  if (i < E) {
    int d = dst[i];
    int pos = rowptr[d] + atomicAdd(&cur[d], 1);
    csr_src[pos] = src[i];
  }
}

// ---------------- wave GEMM cores (bf16 MFMA 16x16x32, 16x64 tile/wave) ----------------
// A bf16 (global or LDS), B = W[out,in] row-major bf16 (acts as B^T), fp32 acc.
__device__ __forceinline__ void wave_gemm(const ushort* __restrict__ A, int lda, int row0,
                                          const ushort* __restrict__ B, int ldb, int col0,
                                          int K, f32x4 acc[4]) {
  int lane = threadIdx.x & 63;
  int m = lane & 15, quad = lane >> 4;
  const ushort* ap = A + (size_t)(row0 + m) * lda + quad * 8;
  const ushort* bp = B + (size_t)(col0 + m) * ldb + quad * 8;
  for (int k0 = 0; k0 < K; k0 += 32) {
    bf8 a = *(const bf8*)(ap + k0);
#pragma unroll
    for (int j = 0; j < 4; ++j) {
      bf8 b = *(const bf8*)(bp + (size_t)j * 16 * ldb + k0);
      acc[j] = __builtin_amdgcn_mfma_f32_16x16x32_bf16(a, b, acc[j], 0, 0, 0);
    }
  }
}

// A fp32 (global), converted to bf16 in-register.
__device__ __forceinline__ void wave_gemm_f32a(const float* __restrict__ A, int lda, int row0,
                                               const ushort* __restrict__ B, int ldb, int col0,
                                               int K, f32x4 acc[4]) {
  int lane = threadIdx.x & 63;
  int m = lane & 15, quad = lane >> 4;
  const float* ap = A + (size_t)(row0 + m) * lda + quad * 8;
  const ushort* bp = B + (size_t)(col0 + m) * ldb + quad * 8;
  for (int k0 = 0; k0 < K; k0 += 32) {
    float4 x0 = *(const float4*)(ap + k0);
    float4 x1 = *(const float4*)(ap + k0 + 4);
    bf8 a;
    a[0] = (short)f2bf(x0.x); a[1] = (short)f2bf(x0.y);
    a[2] = (short)f2bf(x0.z); a[3] = (short)f2bf(x0.w);
    a[4] = (short)f2bf(x1.x); a[5] = (short)f2bf(x1.y);
    a[6] = (short)f2bf(x1.z); a[7] = (short)f2bf(x1.w);
#pragma unroll
    for (int j = 0; j < 4; ++j) {
      bf8 b = *(const bf8*)(bp + (size_t)j * 16 * ldb + k0);
      acc[j] = __builtin_amdgcn_mfma_f32_16x16x32_bf16(a, b, acc[j], 0, 0, 0);
    }
  }
}

// q,k,v = feat @ W{q,k,v}^T + b ; outputs bf16
__global__ __launch_bounds__(256) void k_qkv(const float* __restrict__ feat,
                                             const ushort* __restrict__ Wq, const ushort* __restrict__ Wk,
                                             const ushort* __restrict__ Wv,
                                             const float* __restrict__ bq, const float* __restrict__ bk,
                                             const float* __restrict__ bv,
                                             ushort* __restrict__ q, ushort* __restrict__ k,
                                             ushort* __restrict__ v) {
  int w = blockIdx.x * 4 + (threadIdx.x >> 6);
  int rt = w / 12, ct = w % 12;
  int which = ct >> 2;
  int col0 = (ct & 3) * 64;
  const ushort* W = (which == 0) ? Wq : (which == 1) ? Wk : Wv;
  const float* bias = (which == 0) ? bq : (which == 1) ? bk : bv;
  ushort* outp = (which == 0) ? q : (which == 1) ? k : v;

  f32x4 acc[4];
#pragma unroll
  for (int j = 0; j < 4; ++j) acc[j] = (f32x4){0.f, 0.f, 0.f, 0.f};
  wave_gemm_f32a(feat, CDIM, rt * 16, W, CDIM, col0, CDIM, acc);

  int lane = threadIdx.x & 63, m = lane & 15, quad = lane >> 4;
#pragma unroll
  for (int j = 0; j < 4; ++j) {
    int cc = col0 + j * 16 + m;
    float bs = bias[cc];
#pragma unroll
    for (int i = 0; i < 4; ++i) {
      int r = rt * 16 + quad * 4 + i;
      outp[(size_t)r * CDIM + cc] = f2bf(acc[j][i] + bs);
    }
  }
}

// fused segment softmax + weighted aggregate: one block (256 thr) per dst node.
// softmax shift-invariance: scores clamped to [-10,10], use fixed shift 10 (== exact segment softmax).
__global__ __launch_bounds__(256) void k_edge_agg(const ushort* __restrict__ q,
                                                  const ushort* __restrict__ kk,
                                                  const ushort* __restrict__ vv,
                                                  const int* __restrict__ rowptr,
                                                  const int* __restrict__ csr_src,
                                                  int N,
                                                  ushort* __restrict__ wv) {
  int n = blockIdx.x;
  int c = threadIdx.x;
  float qc = bf2f(q[(size_t)n * CDIM + c]);
  int beg = rowptr[n], end = rowptr[n + 1];
  float acc = 0.f, den = 0.f;
  for (int i = beg; i < end; ++i) {
    int src = csr_src[i];
    src = (src < 0) ? 0 : (src >= N ? N - 1 : src);  // safety clamp
    float kc = bf2f(kk[(size_t)src * CDIM + c]);
    float p = qc * kc;
    p += __shfl_xor(p, 1);
    p += __shfl_xor(p, 2);
    p += __shfl_xor(p, 4);
    p += __shfl_xor(p, 8);
    p += __shfl_xor(p, 16);              // per-head (32-lane) dot
    float s = p * 0.17677669529663687f;  // 1/sqrt(32)
    s = fminf(10.f, fmaxf(-10.f, s));
    float e = __expf(s - 10.f);
    float vc = bf2f(vv[(size_t)src * CDIM + c]);
    acc = fmaf(e, vc, acc);
    den += e;
  }
  float r = (end > beg) ? acc / den : 0.f;
  wv[(size_t)n * CDIM + c] = f2bf(r);
}

// x = feat + wv @ Wp^T + bp   (x fp32)
__global__ __launch_bounds__(256) void k_proj(const ushort* __restrict__ wv,
                                              const ushort* __restrict__ Wp,
                                              const float* __restrict__ bp,
                                              const float* __restrict__ feat,
                                              float* __restrict__ x) {
  int w = blockIdx.x * 4 + (threadIdx.x >> 6);
  int rt = w >> 2, col0 = (w & 3) * 64;
  f32x4 acc[4];
#pragma unroll
  for (int j = 0; j < 4; ++j) acc[j] = (f32x4){0.f, 0.f, 0.f, 0.f};
  wave_gemm(wv, CDIM, rt * 16, Wp, CDIM, col0, CDIM, acc);
  int lane = threadIdx.x & 63, m = lane & 15, quad = lane >> 4;
#pragma unroll
  for (int j = 0; j < 4; ++j) {
    int cc = col0 + j * 16 + m;
    float bs = bp[cc];
#pragma unroll
    for (int i = 0; i < 4; ++i) {
      int r = rt * 16 + quad * 4 + i;
      x[(size_t)r * CDIM + cc] = acc[j][i] + bs + feat[(size_t)r * CDIM + cc];
    }
  }
}

// h = layernorm(x)*g + b -> bf16 ; one wave per row
__global__ __launch_bounds__(256) void k_ln(const float* __restrict__ x,
                                            const float* __restrict__ g,
                                            const float* __restrict__ b,
                                            ushort* __restrict__ h) {
  int row = blockIdx.x * 4 + (threadIdx.x >> 6);
  int lane = threadIdx.x & 63;
  const float* xr = x + (size_t)row * CDIM;
  float4 xv = *(const float4*)(xr + lane * 4);
  float s = xv.x + xv.y + xv.z + xv.w;
  float ss = xv.x * xv.x + xv.y * xv.y + xv.z * xv.z + xv.w * xv.w;
#pragma unroll
  for (int msk = 1; msk <= 32; msk <<= 1) {
    s += __shfl_xor(s, msk);
    ss += __shfl_xor(ss, msk);
  }
  float mu = s * (1.f / CDIM);
  float var = ss * (1.f / CDIM) - mu * mu;
  float rs = rsqrtf(var + 1e-5f);
  float xe[4] = {xv.x, xv.y, xv.z, xv.w};
#pragma unroll
  for (int t = 0; t < 4; ++t) {
    int cc = lane * 4 + t;
    h[(size_t)row * CDIM + cc] = f2bf((xe[t] - mu) * rs * g[cc] + b[cc]);
  }
}

// fused MLP: out = x + gelu(h@W1^T+b1)@W2^T + b2.  Block = 16 rows; hidden tile staged in LDS.
__global__ __launch_bounds__(256) void k_mlp(const ushort* __restrict__ h,
                                             const ushort* __restrict__ W1,
                                             const float* __restrict__ b1,
                                             const ushort* __restrict__ W2,
                                             const float* __restrict__ b2,
                                             const float* __restrict__ x,
                                             float* __restrict__ out) {
  __shared__ ushort sh[16 * HSTRIDE];
  int rt = blockIdx.x;
  int wave = threadIdx.x >> 6;
  int lane = threadIdx.x & 63, m = lane & 15, quad = lane >> 4;

  // phase 1: this wave computes hidden cols [wave*256, wave*256+256), gelu -> LDS
  for (int cg = 0; cg < 4; ++cg) {
    int col0 = wave * 256 + cg * 64;
    f32x4 acc[4];
#pragma unroll
    for (int j = 0; j < 4; ++j) acc[j] = (f32x4){0.f, 0.f, 0.f, 0.f};
    wave_gemm(h, CDIM, rt * 16, W1, CDIM, col0, CDIM, acc);
#pragma unroll
    for (int j = 0; j < 4; ++j) {
      int cc = col0 + j * 16 + m;
      float bs = b1[cc];
#pragma unroll
      for (int i = 0; i < 4; ++i) {
        float t = acc[j][i] + bs;
        float gl = 0.5f * t * (1.f + erff(t * 0.70710678118654752f));
        sh[(quad * 4 + i) * HSTRIDE + cc] = f2bf(gl);
      }
    }
  }
  __syncthreads();

  // phase 2: this wave computes out cols [wave*64, wave*64+64), K=1024 from LDS
  int col0 = wave * 64;
  f32x4 acc[4];
#pragma unroll
  for (int j = 0; j < 4; ++j) acc[j] = (f32x4){0.f, 0.f, 0.f, 0.f};
  wave_gemm(sh, HSTRIDE, 0, W2, 1024, col0, 1024, acc);
#pragma unroll
  for (int j = 0; j < 4; ++j) {
    int cc = col0 + j * 16 + m;
    float bs = b2[cc];
#pragma unroll
    for (int i = 0; i < 4; ++i) {
      int r = rt * 16 + quad * 4 + i;
      out[(size_t)r * CDIM + cc] = x[(size_t)r * CDIM + cc] + acc[j][i] + bs;
    }
  }
}

extern "C" void kernel_launch(void* const* d_in, const int* in_sizes, int n_in,
                              void* d_out, int out_size, void* d_ws, size_t ws_size,
                              hipStream_t stream) {
  const float* feat = (const float*)d_in[0];
  const int* esrc = (const int*)d_in[1];
  const int* edst = (const int*)d_in[2];
  const float* Wq = (const float*)d_in[3];
  const float* bq = (const float*)d_in[4];
  const float* Wk = (const float*)d_in[5];
  const float* bk = (const float*)d_in[6];
  const float* Wv = (const float*)d_in[7];
  const float* bv = (const float*)d_in[8];
  const float* Wp = (const float*)d_in[9];
  const float* bp = (const float*)d_in[10];
  const float* lng = (const float*)d_in[11];
  const float* lnb = (const float*)d_in[12];
  const float* W1 = (const float*)d_in[13];
  const float* b1 = (const float*)d_in[14];
  const float* W2 = (const float*)d_in[15];
  const float* b2 = (const float*)d_in[16];

  const int N = in_sizes[0] / CDIM;  // 50000
  const int E = in_sizes[1];         // 1600000
  const size_t NC2 = (size_t)N * CDIM * 2;  // bf16 node-feature plane: 25.6 MB

  // Workspace layout with lifetime overlays (~111 MB total):
  //   [0,      NC2)  q   (qkv->edge)     } x fp32 (proj->end) overlays q+k
  //   [NC2,  2*NC2)  k   (qkv->edge)     }
  //   [2*NC2,3*NC2)  v   (qkv->edge)     } h bf16 (ln->mlp) overlays v
  //   [3*NC2,4*NC2)  wv  (edge->proj)
  //   [4*NC2, ...)   CSR: rowptr, deg, csr_src, bsum (build->edge)
  //   then bf16 weights (whole call)
  char* w = (char*)d_ws;
  ushort* q  = (ushort*)(w);
  ushort* kk = (ushort*)(w + NC2);
  ushort* vv = (ushort*)(w + 2 * NC2);
  ushort* wvb = (ushort*)(w + 3 * NC2);
  float*  x  = (float*)(w);            // 2*NC2 bytes, overlays q+k
  ushort* h  = (ushort*)(w + 2 * NC2); // overlays v

  char* csr = w + 4 * NC2;
  int* rowptr  = (int*)(csr);                       // (N+1) ints -> reserve 200064
  int* deg     = (int*)(csr + 200064);              // N ints -> reserve 200064
  int* csr_src = (int*)(csr + 400128);              // E ints
  int* bsum    = (int*)(csr + 400128 + (size_t)E * 4);

  char* wb = csr + 400128 + (size_t)E * 4 + 256;
  ushort* Wqb = (ushort*)(wb);
  ushort* Wkb = (ushort*)(wb + 131072);
  ushort* Wvb = (ushort*)(wb + 262144);
  ushort* Wpb = (ushort*)(wb + 393216);
  ushort* W1b = (ushort*)(wb + 524288);
  ushort* W2b = (ushort*)(wb + 1048576);

  const int nb = (N + 1023) / 1024;
  const int RT = N / 16;  // 3125

  // weight casts (independent)
  k_cast<<<(65536 + 255) / 256, 256, 0, stream>>>(Wq, Wqb, 65536);
  k_cast<<<(65536 + 255) / 256, 256, 0, stream>>>(Wk, Wkb, 65536);
  k_cast<<<(65536 + 255) / 256, 256, 0, stream>>>(Wv, Wvb, 65536);
  k_cast<<<(65536 + 255) / 256, 256, 0, stream>>>(Wp, Wpb, 65536);
  k_cast<<<(262144 + 255) / 256, 256, 0, stream>>>(W1, W1b, 262144);
  k_cast<<<(262144 + 255) / 256, 256, 0, stream>>>(W2, W2b, 262144);

  // CSR build (group edges by dst)
  hipMemsetAsync(deg, 0, (size_t)N * 4, stream);
  k_hist<<<(E + 255) / 256, 256, 0, stream>>>(edst, E, deg);
  k_scan1<<<nb, 1024, 0, stream>>>(deg, N, rowptr, bsum);
  k_scan2<<<1, 64, 0, stream>>>(bsum, nb);
  k_scan3<<<(N + 255) / 256, 256, 0, stream>>>(rowptr, bsum, N);
  hipMemsetAsync(deg, 0, (size_t)N * 4, stream);
  k_scatter<<<(E + 255) / 256, 256, 0, stream>>>(esrc, edst, E, rowptr, deg, csr_src);

  // QKV projections
  k_qkv<<<(RT * 12) / 4, 256, 0, stream>>>(feat, Wqb, Wkb, Wvb, bq, bk, bv, q, kk, vv);
  // fused segment-softmax + aggregate
  k_edge_agg<<<N, 256, 0, stream>>>(q, kk, vv, rowptr, csr_src, N, wvb);
  // x = feat + wv@Wp^T + bp   (overwrites q,k region; they are dead)
  k_proj<<<RT, 256, 0, stream>>>(wvb, Wpb, bp, feat, x);
  // h = LN(x)  (overwrites v; dead)
  k_ln<<<N / 4, 256, 0, stream>>>(x, lng, lnb, h);
  // out = x + gelu(h@W1^T+b1)@W2^T + b2  (fused, no hidden buffer)
  k_mlp<<<RT, 256, 0, stream>>>(h, W1b, b1, W2b, b2, x, (float*)d_out);
}

// Round 3
// 1007.270 us; speedup vs baseline: 1.4246x; 1.4246x over previous
//
#include <hip/hip_runtime.h>
#include <hip/hip_bf16.h>

#define CDIM 256
#define NH 8
#define HDIM 32

typedef short bf8 __attribute__((ext_vector_type(8)));
typedef float f32x4 __attribute__((ext_vector_type(4)));

__device__ __forceinline__ float bf2f(ushort u) {
  union { unsigned int i; float f; } x; x.i = ((unsigned int)u) << 16; return x.f;
}
__device__ __forceinline__ ushort f2bf(float f) {
  union { float f; unsigned int i; } x; x.f = f;
  unsigned int lsb = (x.i >> 16) & 1u;
  unsigned int r = x.i + 0x7fffu + lsb;
  return (ushort)(r >> 16);
}

// ---------------- casts fp32 -> bf16 (vectorized) ----------------
__global__ void k_cast4(const float4* __restrict__ s, ushort4* __restrict__ d, int n4) {
  int i = blockIdx.x * blockDim.x + threadIdx.x;
  if (i < n4) {
    float4 v = s[i];
    ushort4 o;
    o.x = f2bf(v.x); o.y = f2bf(v.y); o.z = f2bf(v.z); o.w = f2bf(v.w);
    d[i] = o;
  }
}

// ---------------- CSR build ----------------
__global__ void k_hist(const int* __restrict__ dst, int E, int* __restrict__ deg) {
  int i = blockIdx.x * blockDim.x + threadIdx.x;
  if (i < E) atomicAdd(&deg[dst[i]], 1);
}

__global__ __launch_bounds__(1024) void k_scan1(const int* __restrict__ deg, int N,
                                                int* __restrict__ rowptr, int* __restrict__ bsum) {
  __shared__ int s[1024];
  int t = threadIdx.x;
  int i = blockIdx.x * 1024 + t;
  int val = (i < N) ? deg[i] : 0;
  s[t] = val;
  __syncthreads();
  for (int off = 1; off < 1024; off <<= 1) {
    int add = (t >= off) ? s[t - off] : 0;
    __syncthreads();
    s[t] += add;
    __syncthreads();
  }
  if (i < N) rowptr[i + 1] = s[t];
  if (t == 1023) bsum[blockIdx.x] = s[t];
}

__global__ void k_scan2(int* __restrict__ bsum, int nb) {
  if (threadIdx.x == 0 && blockIdx.x == 0) {
    int run = 0;
    for (int j = 0; j < nb; ++j) { int t = bsum[j]; bsum[j] = run; run += t; }
  }
}

__global__ void k_scan3(int* __restrict__ rowptr, const int* __restrict__ bsum, int N) {
  int i = blockIdx.x * blockDim.x + threadIdx.x;
  if (i < N) rowptr[i + 1] += bsum[i >> 10];
  if (i == 0) rowptr[0] = 0;
}

__global__ void k_scatter(const int* __restrict__ src, const int* __restrict__ dst, int E,
                          const int* __restrict__ rowptr, int* __restrict__ cur,
                          int* __restrict__ csr_src) {
  int i = blockIdx.x * blockDim.x + threadIdx.x;
  if (i < E) {
    int d = dst[i];
    int pos = rowptr[d] + atomicAdd(&cur[d], 1);
    csr_src[pos] = src[i];
  }
}

// ---------------- 64x64-per-wave GEMM tile (bf16 MFMA 16x16x32) ----------------
// A row-major bf16 [nrows x lda], row-clamped; B = W [out,in] row-major bf16 (acts as B^T).
// acc[ri*4+cj]: C rows row0+ri*16+quad*4+i, cols col0+cj*16+m.
__device__ __forceinline__ void wave_tile64(const ushort* __restrict__ A, int lda, int row0, int nrows,
                                            const ushort* __restrict__ B, int ldb, int col0,
                                            int K, f32x4* acc) {
  int lane = threadIdx.x & 63;
  int m = lane & 15, quad = lane >> 4;
  const ushort* ap[4];
  const ushort* bp[4];
#pragma unroll
  for (int ri = 0; ri < 4; ++ri) {
    int r = row0 + ri * 16 + m;
    r = (r < nrows) ? r : (nrows - 1);
    ap[ri] = A + (size_t)r * lda + quad * 8;
  }
#pragma unroll
  for (int cj = 0; cj < 4; ++cj)
    bp[cj] = B + (size_t)(col0 + cj * 16 + m) * ldb + quad * 8;
  for (int k0 = 0; k0 < K; k0 += 32) {
    bf8 a[4], b[4];
#pragma unroll
    for (int ri = 0; ri < 4; ++ri) a[ri] = *(const bf8*)(ap[ri] + k0);
#pragma unroll
    for (int cj = 0; cj < 4; ++cj) b[cj] = *(const bf8*)(bp[cj] + k0);
#pragma unroll
    for (int ri = 0; ri < 4; ++ri)
#pragma unroll
      for (int cj = 0; cj < 4; ++cj)
        acc[ri * 4 + cj] = __builtin_amdgcn_mfma_f32_16x16x32_bf16(a[ri], b[cj], acc[ri * 4 + cj], 0, 0, 0);
  }
}

// 32-row variant (ri in 0..1), A global
__device__ __forceinline__ void wave_tile32g(const ushort* __restrict__ A, int lda, int row0, int nrows,
                                             const ushort* __restrict__ B, int ldb, int col0,
                                             int K, f32x4* acc) {
  int lane = threadIdx.x & 63;
  int m = lane & 15, quad = lane >> 4;
  const ushort* ap[2];
  const ushort* bp[4];
#pragma unroll
  for (int ri = 0; ri < 2; ++ri) {
    int r = row0 + ri * 16 + m;
    r = (r < nrows) ? r : (nrows - 1);
    ap[ri] = A + (size_t)r * lda + quad * 8;
  }
#pragma unroll
  for (int cj = 0; cj < 4; ++cj)
    bp[cj] = B + (size_t)(col0 + cj * 16 + m) * ldb + quad * 8;
  for (int k0 = 0; k0 < K; k0 += 32) {
    bf8 a[2], b[4];
#pragma unroll
    for (int ri = 0; ri < 2; ++ri) a[ri] = *(const bf8*)(ap[ri] + k0);
#pragma unroll
    for (int cj = 0; cj < 4; ++cj) b[cj] = *(const bf8*)(bp[cj] + k0);
#pragma unroll
    for (int ri = 0; ri < 2; ++ri)
#pragma unroll
      for (int cj = 0; cj < 4; ++cj)
        acc[ri * 4 + cj] = __builtin_amdgcn_mfma_f32_16x16x32_bf16(a[ri], b[cj], acc[ri * 4 + cj], 0, 0, 0);
  }
}

// q,k,v = feat @ W{q,k,v}^T + b ; block = 64 rows x 256 cols of one of q/k/v
__global__ __launch_bounds__(256) void k_qkv(const ushort* __restrict__ featb,
                                             const ushort* __restrict__ Wq, const ushort* __restrict__ Wk,
                                             const ushort* __restrict__ Wv,
                                             const float* __restrict__ bq, const float* __restrict__ bk,
                                             const float* __restrict__ bv,
                                             ushort* __restrict__ q, ushort* __restrict__ k,
                                             ushort* __restrict__ v, int N) {
  int rt = blockIdx.x, which = blockIdx.y;
  const ushort* W = (which == 0) ? Wq : (which == 1) ? Wk : Wv;
  const float* bias = (which == 0) ? bq : (which == 1) ? bk : bv;
  ushort* outp = (which == 0) ? q : (which == 1) ? k : v;
  int wave = threadIdx.x >> 6, lane = threadIdx.x & 63, m = lane & 15, quad = lane >> 4;
  int row0 = rt * 64, col0 = wave * 64;

  f32x4 acc[16];
#pragma unroll
  for (int j = 0; j < 16; ++j) acc[j] = (f32x4){0.f, 0.f, 0.f, 0.f};
  wave_tile64(featb, CDIM, row0, N, W, CDIM, col0, CDIM, acc);

#pragma unroll
  for (int cj = 0; cj < 4; ++cj) {
    int cc = col0 + cj * 16 + m;
    float bs = bias[cc];
#pragma unroll
    for (int ri = 0; ri < 4; ++ri)
#pragma unroll
      for (int i = 0; i < 4; ++i) {
        int r = row0 + ri * 16 + quad * 4 + i;
        if (r < N) outp[(size_t)r * CDIM + cc] = f2bf(acc[ri * 4 + cj][i] + bs);
      }
  }
}

// fused segment softmax + aggregate: one block (256 thr) per dst node, two-phase, no shfl chains.
__global__ __launch_bounds__(256) void k_edge_agg(const ushort* __restrict__ q,
                                                  const ushort* __restrict__ kk,
                                                  const ushort* __restrict__ vv,
                                                  const int* __restrict__ rowptr,
                                                  const int* __restrict__ csr_src,
                                                  int N,
                                                  ushort* __restrict__ wv) {
  __shared__ float e_T[8 * 36];   // [head][36] padded, 16B-aligned groups of 4
  __shared__ int srcs[32];
  __shared__ float wdens[32];

  int n = blockIdx.x;
  int t = threadIdx.x;
  int lane = t & 63, wave = t >> 6;
  int el = t >> 3, h = t & 7;      // phase-A role: edge-slot, head
  int h2 = t >> 5;                  // phase-B role: head of channel t

  int beg = rowptr[n], end = rowptr[n + 1];
  int deg = end - beg;

  // q slice for (this thread's head) into registers, f32
  float qf[32];
  {
    const ushort* qp = q + (size_t)n * CDIM + h * HDIM;
#pragma unroll
    for (int g = 0; g < 4; ++g) {
      bf8 qv = *(const bf8*)(qp + g * 8);
#pragma unroll
      for (int j = 0; j < 8; ++j) qf[g * 8 + j] = bf2f((ushort)qv[j]);
    }
  }

  float accv = 0.f;      // phase-B accumulator for channel t
  float den_part = 0.f;  // phase-A partial denominator for (el,h)

  int nch = (deg + 31) >> 5;
  for (int ch = 0; ch < nch; ++ch) {
    int eidx = beg + ch * 32 + el;
    int src = 0;
    float e = 0.f;
    if (eidx < end) {
      src = csr_src[eidx];
      const ushort* kp = kk + (size_t)src * CDIM + h * HDIM;
      float dot = 0.f;
#pragma unroll
      for (int g = 0; g < 4; ++g) {
        bf8 kv = *(const bf8*)(kp + g * 8);
#pragma unroll
        for (int j = 0; j < 8; ++j) dot = fmaf(qf[g * 8 + j], bf2f((ushort)kv[j]), dot);
      }
      float s = dot * 0.17677669529663687f;  // 1/sqrt(32)
      s = fminf(10.f, fmaxf(-10.f, s));
      e = __expf(s - 10.f);  // fixed shift: softmax shift-invariant, scores clamped
    }
    e_T[h * 36 + el] = e;
    if (h == 0) srcs[el] = src;
    den_part += e;
    __syncthreads();

    // phase B: channel-parallel aggregate of these 32 edges
#pragma unroll
    for (int g4 = 0; g4 < 8; ++g4) {
      int4 s4 = *(const int4*)&srcs[g4 * 4];
      float4 e4 = *(const float4*)&e_T[h2 * 36 + g4 * 4];
      accv = fmaf(e4.x, bf2f(vv[(size_t)s4.x * CDIM + t]), accv);
      accv = fmaf(e4.y, bf2f(vv[(size_t)s4.y * CDIM + t]), accv);
      accv = fmaf(e4.z, bf2f(vv[(size_t)s4.z * CDIM + t]), accv);
      accv = fmaf(e4.w, bf2f(vv[(size_t)s4.w * CDIM + t]), accv);
    }
    __syncthreads();
  }

  // denominator: reduce den_part over el (lanes with equal lane&7, then across waves)
  float d = den_part;
  d += __shfl_xor(d, 8);
  d += __shfl_xor(d, 16);
  d += __shfl_xor(d, 32);
  if (lane < 8) wdens[wave * 8 + lane] = d;
  __syncthreads();
  float den = wdens[h2] + wdens[8 + h2] + wdens[16 + h2] + wdens[24 + h2];
  wv[(size_t)n * CDIM + t] = f2bf((deg > 0) ? accv / den : 0.f);
}

// x = feat + wv @ Wp^T + bp  (fp32 out); block = 64 rows x 256 cols
__global__ __launch_bounds__(256) void k_proj(const ushort* __restrict__ wv,
                                              const ushort* __restrict__ Wp,
                                              const float* __restrict__ bp,
                                              const float* __restrict__ feat,
                                              float* __restrict__ x, int N) {
  int rt = blockIdx.x;
  int wave = threadIdx.x >> 6, lane = threadIdx.x & 63, m = lane & 15, quad = lane >> 4;
  int row0 = rt * 64, col0 = wave * 64;
  f32x4 acc[16];
#pragma unroll
  for (int j = 0; j < 16; ++j) acc[j] = (f32x4){0.f, 0.f, 0.f, 0.f};
  wave_tile64(wv, CDIM, row0, N, Wp, CDIM, col0, CDIM, acc);
#pragma unroll
  for (int cj = 0; cj < 4; ++cj) {
    int cc = col0 + cj * 16 + m;
    float bs = bp[cc];
#pragma unroll
    for (int ri = 0; ri < 4; ++ri)
#pragma unroll
      for (int i = 0; i < 4; ++i) {
        int r = row0 + ri * 16 + quad * 4 + i;
        if (r < N) x[(size_t)r * CDIM + cc] = acc[ri * 4 + cj][i] + bs + feat[(size_t)r * CDIM + cc];
      }
  }
}

// h = layernorm(x)*g + b -> bf16 ; one wave per row
__global__ __launch_bounds__(256) void k_ln(const float* __restrict__ x,
                                            const float* __restrict__ g,
                                            const float* __restrict__ b,
                                            ushort* __restrict__ h) {
  int row = blockIdx.x * 4 + (threadIdx.x >> 6);
  int lane = threadIdx.x & 63;
  const float* xr = x + (size_t)row * CDIM;
  float4 xv = *(const float4*)(xr + lane * 4);
  float s = xv.x + xv.y + xv.z + xv.w;
  float ss = xv.x * xv.x + xv.y * xv.y + xv.z * xv.z + xv.w * xv.w;
#pragma unroll
  for (int msk = 1; msk <= 32; msk <<= 1) {
    s += __shfl_xor(s, msk);
    ss += __shfl_xor(ss, msk);
  }
  float mu = s * (1.f / CDIM);
  float var = ss * (1.f / CDIM) - mu * mu;
  float rs = rsqrtf(var + 1e-5f);
  float xe[4] = {xv.x, xv.y, xv.z, xv.w};
#pragma unroll
  for (int t = 0; t < 4; ++t) {
    int cc = lane * 4 + t;
    h[(size_t)row * CDIM + cc] = f2bf((xe[t] - mu) * rs * g[cc] + b[cc]);
  }
}

// fused MLP: out = x + gelu(h@W1^T+b1)@W2^T + b2. Block = 32 rows; hidden (32x1024 bf16)
// in LDS with XOR-swizzled 16B granules to kill the power-of-2 stride bank conflicts.
#define SHST 1024
__global__ __launch_bounds__(256) void k_mlp(const ushort* __restrict__ h,
                                             const ushort* __restrict__ W1,
                                             const float* __restrict__ b1,
                                             const ushort* __restrict__ W2,
                                             const float* __restrict__ b2,
                                             const float* __restrict__ x,
                                             float* __restrict__ out, int N) {
  __shared__ ushort sh[32 * SHST];  // 64 KB
  int rt = blockIdx.x;
  int row0 = rt * 32;
  int wave = threadIdx.x >> 6, lane = threadIdx.x & 63, m = lane & 15, quad = lane >> 4;

  // phase 1: wave computes hidden cols [wave*256, +256) as 4 tiles of 32x64
  for (int cg = 0; cg < 4; ++cg) {
    int col0 = wave * 256 + cg * 64;
    f32x4 acc[8];
#pragma unroll
    for (int j = 0; j < 8; ++j) acc[j] = (f32x4){0.f, 0.f, 0.f, 0.f};
    wave_tile32g(h, CDIM, row0, N, W1, CDIM, col0, CDIM, acc);
#pragma unroll
    for (int cj = 0; cj < 4; ++cj) {
      int cc = col0 + cj * 16 + m;
      float bs = b1[cc];
#pragma unroll
      for (int ri = 0; ri < 2; ++ri)
#pragma unroll
        for (int i = 0; i < 4; ++i) {
          int lr = ri * 16 + quad * 4 + i;
          float tt = acc[ri * 4 + cj][i] + bs;
          float gl = 0.5f * tt * (1.f + erff(tt * 0.70710678118654752f));
          int sc = ((((cc >> 3) ^ (lr & 7)) << 3) | (cc & 7));
          sh[lr * SHST + sc] = f2bf(gl);
        }
    }
  }
  __syncthreads();

  // phase 2: wave computes out cols [wave*64, +64), K=1024, A from swizzled LDS
  int col0 = wave * 64;
  f32x4 acc[8];
#pragma unroll
  for (int j = 0; j < 8; ++j) acc[j] = (f32x4){0.f, 0.f, 0.f, 0.f};
  const ushort* bp[4];
#pragma unroll
  for (int cj = 0; cj < 4; ++cj)
    bp[cj] = W2 + (size_t)(col0 + cj * 16 + m) * 1024 + quad * 8;
  for (int k0 = 0; k0 < 1024; k0 += 32) {
    int g = (k0 >> 3) + quad;
    bf8 a[2], b[4];
#pragma unroll
    for (int ri = 0; ri < 2; ++ri) {
      int lr = ri * 16 + m;
      a[ri] = *(const bf8*)&sh[lr * SHST + ((g ^ (lr & 7)) << 3)];
    }
#pragma unroll
    for (int cj = 0; cj < 4; ++cj) b[cj] = *(const bf8*)(bp[cj] + k0);
#pragma unroll
    for (int ri = 0; ri < 2; ++ri)
#pragma unroll
      for (int cj = 0; cj < 4; ++cj)
        acc[ri * 4 + cj] = __builtin_amdgcn_mfma_f32_16x16x32_bf16(a[ri], b[cj], acc[ri * 4 + cj], 0, 0, 0);
  }
#pragma unroll
  for (int cj = 0; cj < 4; ++cj) {
    int cc = col0 + cj * 16 + m;
    float bs = b2[cc];
#pragma unroll
    for (int ri = 0; ri < 2; ++ri)
#pragma unroll
      for (int i = 0; i < 4; ++i) {
        int r = row0 + ri * 16 + quad * 4 + i;
        if (r < N) out[(size_t)r * CDIM + cc] = x[(size_t)r * CDIM + cc] + acc[ri * 4 + cj][i] + bs;
      }
  }
}

extern "C" void kernel_launch(void* const* d_in, const int* in_sizes, int n_in,
                              void* d_out, int out_size, void* d_ws, size_t ws_size,
                              hipStream_t stream) {
  const float* feat = (const float*)d_in[0];
  const int* esrc = (const int*)d_in[1];
  const int* edst = (const int*)d_in[2];
  const float* Wq = (const float*)d_in[3];
  const float* bq = (const float*)d_in[4];
  const float* Wk = (const float*)d_in[5];
  const float* bk = (const float*)d_in[6];
  const float* Wv = (const float*)d_in[7];
  const float* bv = (const float*)d_in[8];
  const float* Wp = (const float*)d_in[9];
  const float* bp = (const float*)d_in[10];
  const float* lng = (const float*)d_in[11];
  const float* lnb = (const float*)d_in[12];
  const float* W1 = (const float*)d_in[13];
  const float* b1 = (const float*)d_in[14];
  const float* W2 = (const float*)d_in[15];
  const float* b2 = (const float*)d_in[16];

  const int N = in_sizes[0] / CDIM;  // 50000
  const int E = in_sizes[1];         // 1600000
  const size_t NC2 = (size_t)N * CDIM * 2;  // bf16 plane: 25.6 MB

  // Workspace (~112 MB, lifetime overlays):
  //   [0,NC2) q | x(f32,2*NC2) overlays q+k from proj on
  //   [NC2,2NC2) k
  //   [2NC2,3NC2) v | h(bf16) overlays v from ln on
  //   [3NC2,4NC2) wv | featb(bf16) overlays (dead before edge_agg writes wv)
  //   [4NC2,..) CSR, then bf16 weights
  char* w = (char*)d_ws;
  ushort* q   = (ushort*)(w);
  ushort* kk  = (ushort*)(w + NC2);
  ushort* vv  = (ushort*)(w + 2 * NC2);
  ushort* wvb = (ushort*)(w + 3 * NC2);
  ushort* featb = (ushort*)(w + 3 * NC2);  // overlays wv (disjoint lifetime)
  float*  x   = (float*)(w);               // overlays q+k
  ushort* h   = (ushort*)(w + 2 * NC2);    // overlays v

  char* csr = w + 4 * NC2;
  int* rowptr  = (int*)(csr);
  int* deg     = (int*)(csr + 200064);
  int* csr_src = (int*)(csr + 400128);
  int* bsum    = (int*)(csr + 400128 + (size_t)E * 4);

  char* wb = csr + 400128 + (size_t)E * 4 + 256;
  ushort* Wqb = (ushort*)(wb);
  ushort* Wkb = (ushort*)(wb + 131072);
  ushort* Wvb = (ushort*)(wb + 262144);
  ushort* Wpb = (ushort*)(wb + 393216);
  ushort* W1b = (ushort*)(wb + 524288);
  ushort* W2b = (ushort*)(wb + 1048576);

  const int nb = (N + 1023) / 1024;
  const int RT64 = (N + 63) / 64;   // 782
  const int RT32 = (N + 31) / 32;   // 1563

  // weight + feat casts
  k_cast4<<<(16384 + 255) / 256, 256, 0, stream>>>((const float4*)Wq, (ushort4*)Wqb, 16384);
  k_cast4<<<(16384 + 255) / 256, 256, 0, stream>>>((const float4*)Wk, (ushort4*)Wkb, 16384);
  k_cast4<<<(16384 + 255) / 256, 256, 0, stream>>>((const float4*)Wv, (ushort4*)Wvb, 16384);
  k_cast4<<<(16384 + 255) / 256, 256, 0, stream>>>((const float4*)Wp, (ushort4*)Wpb, 16384);
  k_cast4<<<(65536 + 255) / 256, 256, 0, stream>>>((const float4*)W1, (ushort4*)W1b, 65536);
  k_cast4<<<(65536 + 255) / 256, 256, 0, stream>>>((const float4*)W2, (ushort4*)W2b, 65536);
  {
    int n4 = N * CDIM / 4;
    k_cast4<<<(n4 + 255) / 256, 256, 0, stream>>>((const float4*)feat, (ushort4*)featb, n4);
  }

  // CSR build (group edges by dst)
  hipMemsetAsync(deg, 0, (size_t)N * 4, stream);
  k_hist<<<(E + 255) / 256, 256, 0, stream>>>(edst, E, deg);
  k_scan1<<<nb, 1024, 0, stream>>>(deg, N, rowptr, bsum);
  k_scan2<<<1, 64, 0, stream>>>(bsum, nb);
  k_scan3<<<(N + 255) / 256, 256, 0, stream>>>(rowptr, bsum, N);
  hipMemsetAsync(deg, 0, (size_t)N * 4, stream);
  k_scatter<<<(E + 255) / 256, 256, 0, stream>>>(esrc, edst, E, rowptr, deg, csr_src);

  // QKV projections (featb dead after this; wv region then reusable)
  k_qkv<<<dim3(RT64, 3), 256, 0, stream>>>(featb, Wqb, Wkb, Wvb, bq, bk, bv, q, kk, vv, N);
  // fused segment-softmax + aggregate
  k_edge_agg<<<N, 256, 0, stream>>>(q, kk, vv, rowptr, csr_src, N, wvb);
  // x = feat + wv@Wp^T + bp
  k_proj<<<RT64, 256, 0, stream>>>(wvb, Wpb, bp, feat, x, N);
  // h = LN(x)
  k_ln<<<N / 4, 256, 0, stream>>>(x, lng, lnb, h);
  // out = x + gelu(h@W1^T+b1)@W2^T + b2 (fused through LDS)
  k_mlp<<<RT32, 256, 0, stream>>>(h, W1b, b1, W2b, b2, x, (float*)d_out, N);
}